// Round 4
// baseline (344.068 us; speedup 1.0000x reference)
//
#include <hip/hip_runtime.h>

#define T_LEN 1024

typedef _Float16 f16x8 __attribute__((ext_vector_type(8)));
typedef float    f32x4 __attribute__((ext_vector_type(4)));
typedef int      i32x4 __attribute__((ext_vector_type(4)));

// Software tanh(v) where the input is pre-scaled: t = v * 2*log2(e) (folded into MFMA).
// tanh(v) = 1 - 2/(exp2(t)+1), exp2 via magic-add range reduction + deg-4 Taylor,
// reciprocal via bit-trick + 3 Newton iterations. Zero transcendental (1/8-rate) ops.
__device__ __forceinline__ f32x4 tanh_from_t(f32x4 t) {
    const float MAGIC = 12582912.0f;            // 1.5 * 2^23
    // round-to-nearest-even integer split: t = i + f, f in [-0.5, 0.5]
    f32x4 m  = t + MAGIC;
    f32x4 fi = m - MAGIC;
    f32x4 f  = t - fi;
    // exact 2^i: exponent from the magic-add mantissa bits
    i32x4 ib = __builtin_bit_cast(i32x4, m) - 0x4B400000;   // = i (two's complement)
    i32x4 sb = (ib + 127) << 23;
    f32x4 scale = __builtin_bit_cast(f32x4, sb);
    // 2^f, deg-4 Taylor (rel err <= ~8e-5 on [-0.5,0.5])
    const float C1 = 0.69314718056f, C2 = 0.24022650696f,
                C3 = 0.05550410866f, C4 = 0.00961812911f;
    f32x4 p = __builtin_elementwise_fma(f, (f32x4)C4, (f32x4)C3);
    p = __builtin_elementwise_fma(f, p, (f32x4)C2);
    p = __builtin_elementwise_fma(f, p, (f32x4)C1);
    p = __builtin_elementwise_fma(f, p, (f32x4)1.0f);
    f32x4 E = scale * p;                         // exp2(t), exact power-of-2 scale
    // r = 1/(E+1) via bit-trick estimate + 3 Newtons (rel err ~4e-8)
    f32x4 d = E + 1.0f;
    i32x4 rb = 0x7EF311C3 - __builtin_bit_cast(i32x4, d);
    f32x4 r = __builtin_bit_cast(f32x4, rb);
#pragma unroll
    for (int it = 0; it < 3; ++it) {
        f32x4 q = __builtin_elementwise_fma(-d, r, (f32x4)2.0f);
        r = r * q;
    }
    return __builtin_elementwise_fma(r, (f32x4)(-2.0f), (f32x4)1.0f);
}

// One wave (64 threads) per block; block owns 16 batch rows for all T steps.
// Recurrence as C[m][n] = sum_k Whh[sigma(m)][k] * h[n][k] via mfma_f32_16x16x32_f16:
//   A-frag: A[m=lane&15][k=quad*8+j] = K*Whh[sigma(m)][k]  (static, f16, K=2log2e folded)
//   B-frag: B[k=quad*8+j][n=lane&15] = h[row n][k]         (recirculated in-register)
//   C-frag: col n=lane&15 (batch row), row m=quad*4+reg (h index via sigma)
// sigma0(m)=8*(m>>2)+(m&3), sigma1=sigma0+4  ==> lane's C outputs are exactly
// h[n][8*quad + 0..7] == its own B-fragment slots for the next step. No LDS/shuffle.
__global__ __launch_bounds__(64) void rnn_fused(
    const float* __restrict__ x,      // [B, T]
    const float* __restrict__ W_ih,   // [32,1]
    const float* __restrict__ W_hh,   // [32,32]
    const float* __restrict__ b_ih,   // [32]
    const float* __restrict__ b_hh,   // [32]
    const float* __restrict__ fc_w,   // [1,32]
    const float* __restrict__ fc_b,   // [1]
    float* __restrict__ out)          // [B]
{
    const int lane = threadIdx.x;
    const int n = lane & 15;   // batch row within tile (B-frag col / C col)
    const int q = lane >> 4;   // quad index

    const float K = 2.88539008177792681472f;   // 2*log2(e), folded into A and C-init

    // A fragments (W_hh rows, permuted by sigma), pre-scaled by K, f16.
    const int c0row = 8 * (n >> 2) + (n & 3);
    const int c1row = c0row + 4;
    f16x8 a0, a1;
#pragma unroll
    for (int j = 0; j < 8; ++j) {
        a0[j] = (_Float16)(K * W_hh[c0row * 32 + q * 8 + j]);
        a1[j] = (_Float16)(K * W_hh[c1row * 32 + q * 8 + j]);
    }

    // This lane produces h-columns c = 8q + i (i = 0..7), as two f32x4 groups.
    f32x4 wih0, wih1, bias0, bias1, fcw0, fcw1;
#pragma unroll
    for (int i = 0; i < 4; ++i) {
        int c = 8 * q + i;
        wih0[i]  = K * W_ih[c];         wih1[i]  = K * W_ih[c + 4];
        bias0[i] = K * (b_ih[c] + b_hh[c]);
        bias1[i] = K * (b_ih[c + 4] + b_hh[c + 4]);
        fcw0[i]  = fc_w[c];             fcw1[i]  = fc_w[c + 4];
    }

    const float* xrow = x + (size_t)(blockIdx.x * 16 + n) * T_LEN;
    float4 xa = *(const float4*)xrow;   // t = 0..3 (4 lanes/row redundant -> broadcast)

    f16x8 hb = {};          // B fragment: h[n][8q+j], starts at 0
    f32x4 hl0 = {}, hl1 = {};           // last-step h in fp32 (for the head)

    for (int t4 = 0; t4 < T_LEN / 4; ++t4) {
        const int nt4 = (t4 < T_LEN / 4 - 1) ? t4 + 1 : t4;   // prefetch next x chunk
        float4 xn = *(const float4*)(xrow + (size_t)nt4 * 4);
#pragma unroll
        for (int p = 0; p < 4; ++p) {
            const float xt = (p == 0) ? xa.x : (p == 1) ? xa.y : (p == 2) ? xa.z : xa.w;
            const f32x4 xt4 = {xt, xt, xt, xt};
            // C-init = K*(x*W_ih + b): v_pk_fma_f32
            f32x4 acc0 = __builtin_elementwise_fma(xt4, wih0, bias0);
            f32x4 acc1 = __builtin_elementwise_fma(xt4, wih1, bias1);
            // acc = K * pre-activation (K folded into A and C-init)
            acc0 = __builtin_amdgcn_mfma_f32_16x16x32_f16(a0, hb, acc0, 0, 0, 0);
            acc1 = __builtin_amdgcn_mfma_f32_16x16x32_f16(a1, hb, acc1, 0, 0, 0);

            hl0 = tanh_from_t(acc0);
            hl1 = tanh_from_t(acc1);

            f16x8 nb;
#pragma unroll
            for (int i = 0; i < 4; ++i) {
                nb[i]     = (_Float16)hl0[i];   // v_cvt_f16_f32 (RNE)
                nb[4 + i] = (_Float16)hl1[i];
            }
            hb = nb;
        }
        xa = xn;
    }

    // Head: out[r] = sum_c h[r][c] * fc_w[c] + fc_b  (use fp32 h values)
    float part = 0.0f;
#pragma unroll
    for (int i = 0; i < 4; ++i) {
        part = fmaf(hl0[i], fcw0[i], part);
        part = fmaf(hl1[i], fcw1[i], part);
    }
    part += __shfl_xor(part, 16);
    part += __shfl_xor(part, 32);
    if (q == 0) out[blockIdx.x * 16 + n] = part + fc_b[0];
}

extern "C" void kernel_launch(void* const* d_in, const int* in_sizes, int n_in,
                              void* d_out, int out_size, void* d_ws, size_t ws_size,
                              hipStream_t stream) {
    const float* x    = (const float*)d_in[0];
    const float* W_ih = (const float*)d_in[1];
    const float* W_hh = (const float*)d_in[2];
    const float* b_ih = (const float*)d_in[3];
    const float* b_hh = (const float*)d_in[4];
    const float* fc_w = (const float*)d_in[5];
    const float* fc_b = (const float*)d_in[6];
    float* out = (float*)d_out;

    const int B = in_sizes[0] / T_LEN;   // 16384
    rnn_fused<<<B / 16, 64, 0, stream>>>(x, W_ih, W_hh, b_ih, b_hh, fc_w, fc_b, out);
}

// Round 5
// 340.303 us; speedup vs baseline: 1.0111x; 1.0111x over previous
//
#include <hip/hip_runtime.h>

#define T_LEN 1024

typedef _Float16 f16x8 __attribute__((ext_vector_type(8)));
typedef float    f32x4 __attribute__((ext_vector_type(4)));
typedef float    f32x2 __attribute__((ext_vector_type(2)));
typedef double   f64x2 __attribute__((ext_vector_type(2)));
typedef unsigned u32x2 __attribute__((ext_vector_type(2)));

// ---- packed-f32 VOP3P ops (compiler won't form these from vector IR; force via asm) ----
__device__ __forceinline__ double pk_fma(double a, double b, double c) {
    double d;
    asm("v_pk_fma_f32 %0, %1, %2, %3" : "=v"(d) : "v"(a), "v"(b), "v"(c));
    return d;
}
__device__ __forceinline__ double pk_mul(double a, double b) {
    double d;
    asm("v_pk_mul_f32 %0, %1, %2" : "=v"(d) : "v"(a), "v"(b));
    return d;
}
__device__ __forceinline__ double pk_add(double a, double b) {
    double d;
    asm("v_pk_add_f32 %0, %1, %2" : "=v"(d) : "v"(a), "v"(b));
    return d;
}
__device__ __forceinline__ double dup2(float c) {
    f32x2 v = {c, c};
    return __builtin_bit_cast(double, v);
}

struct TanhK {   // broadcast-pair constants, materialized once before the T loop
    double M, negM, negONE, ONE, TWO, negTWO, C1, C2, C3, C4;
};

// tanh(v) with t = 2*log2(e)*v pre-scaled (folded into MFMA A/C-init).
// tanh = 1 - 2/(exp2(t)+1). exp2: magic-add RNE split t=i+f, deg-4 Taylor 2^f,
// exact 2^i via (bits(m)<<23)+0x3F800000. rcp: bit-trick seed + 2 sign-flipped
// Newtons. Zero transcendental instructions; all f32 math packed 2/instr.
__device__ __forceinline__ double tanh_pk(double t, const TanhK& k) {
    double m  = pk_add(t, k.M);          // RNE to integer (magic add)
    double fi = pk_add(m, k.negM);       // i as float
    double f  = pk_fma(fi, k.negONE, t); // f = t - i, exact, in [-0.5, 0.5]
    u32x2 mb  = __builtin_bit_cast(u32x2, m);
    u32x2 sb  = (mb << 23) + 0x3F800000u;            // (i+127)<<23, 1 op/elem
    double scale = __builtin_bit_cast(double, sb);   // 2^i exact
    double p = pk_fma(f, k.C4, k.C3);
    p = pk_fma(f, p, k.C2);
    p = pk_fma(f, p, k.C1);
    p = pk_fma(f, p, k.ONE);             // 2^f, rel err <= ~4e-5
    double E = pk_mul(scale, p);         // exp2(t)
    double d = pk_add(E, k.ONE);
    u32x2 db = __builtin_bit_cast(u32x2, d);
    u32x2 rb = 0x7EF311C3u - db;                     // ~5% rcp seed
    double r = __builtin_bit_cast(double, rb);
    double s1  = pk_fma(d, r, k.negTWO); // d*r - 2   = -q1
    double r1n = pk_mul(r, s1);          // -r1
    double q2  = pk_fma(d, r1n, k.TWO);  // 2 - d*r1  =  q2
    double r2n = pk_mul(r1n, q2);        // -r2  (rel err ~6e-6)
    return pk_fma(r2n, k.TWO, k.ONE);    // 1 - 2*r2 = tanh
}

// One wave (64 threads) per block; block owns 16 batch rows for all T steps.
// Recurrence as C[m][n] = sum_k Whh[sigma(m)][k] * h[n][k] via mfma_f32_16x16x32_f16:
//   A-frag: A[m=lane&15][k=quad*8+j] = K*Whh[sigma(m)][k]  (static, f16, K=2log2e folded)
//   B-frag: B[k=quad*8+j][n=lane&15] = h[row n][k]         (recirculated in-register)
//   C-frag: col n=lane&15 (batch row), row m=quad*4+reg (h index via sigma)
// sigma0(m)=8*(m>>2)+(m&3), sigma1=sigma0+4  ==> lane's C outputs are exactly
// h[n][8*quad + 0..7] == its own B-fragment slots for the next step. No LDS/shuffle.
__global__ __launch_bounds__(64) void rnn_fused(
    const float* __restrict__ x,      // [B, T]
    const float* __restrict__ W_ih,   // [32,1]
    const float* __restrict__ W_hh,   // [32,32]
    const float* __restrict__ b_ih,   // [32]
    const float* __restrict__ b_hh,   // [32]
    const float* __restrict__ fc_w,   // [1,32]
    const float* __restrict__ fc_b,   // [1]
    float* __restrict__ out)          // [B]
{
    const int lane = threadIdx.x;
    const int n = lane & 15;   // batch row within tile (B-frag col / C col)
    const int q = lane >> 4;   // quad index

    const float K = 2.88539008177792681472f;   // 2*log2(e)

    TanhK k;
    k.M      = dup2(12582912.0f);   // 1.5 * 2^23
    k.negM   = dup2(-12582912.0f);
    k.negONE = dup2(-1.0f);
    k.ONE    = dup2(1.0f);
    k.TWO    = dup2(2.0f);
    k.negTWO = dup2(-2.0f);
    k.C1 = dup2(0.69314718056f);    // ln2
    k.C2 = dup2(0.24022650696f);    // ln2^2/2
    k.C3 = dup2(0.05550410866f);    // ln2^3/6
    k.C4 = dup2(0.00961812911f);    // ln2^4/24

    // A fragments (W_hh rows, permuted by sigma), pre-scaled by K, f16.
    const int c0row = 8 * (n >> 2) + (n & 3);
    const int c1row = c0row + 4;
    f16x8 a0, a1;
#pragma unroll
    for (int j = 0; j < 8; ++j) {
        a0[j] = (_Float16)(K * W_hh[c0row * 32 + q * 8 + j]);
        a1[j] = (_Float16)(K * W_hh[c1row * 32 + q * 8 + j]);
    }

    // This lane produces h-columns c = 8q + i (i = 0..7): 4 packed pairs.
    double wih[4], bias[4];
#pragma unroll
    for (int g = 0; g < 4; ++g) {
        int c = 8 * q + 2 * g;
        f32x2 w = {K * W_ih[c], K * W_ih[c + 1]};
        f32x2 b = {K * (b_ih[c] + b_hh[c]), K * (b_ih[c + 1] + b_hh[c + 1])};
        wih[g]  = __builtin_bit_cast(double, w);
        bias[g] = __builtin_bit_cast(double, b);
    }

    const float* xrow = x + (size_t)(blockIdx.x * 16 + n) * T_LEN;
    float4 xa = *(const float4*)xrow;   // t = 0..3 (4 lanes/row redundant -> broadcast)

    f16x8 hb = {};                      // B fragment: h[n][8q+j], starts at 0
    double h01 = 0, h23 = 0, h45 = 0, h67 = 0;   // last-step h (fp32 pairs) for head

    for (int t4 = 0; t4 < T_LEN / 4; ++t4) {
        const int nt4 = (t4 < T_LEN / 4 - 1) ? t4 + 1 : t4;   // prefetch next x chunk
        float4 xn = *(const float4*)(xrow + (size_t)nt4 * 4);
#pragma unroll
        for (int p = 0; p < 4; ++p) {
            const float xt = (p == 0) ? xa.x : (p == 1) ? xa.y : (p == 2) ? xa.z : xa.w;
            const double xt2 = dup2(xt);
            // C-init = K*(x*W_ih + b), packed
            double i01 = pk_fma(xt2, wih[0], bias[0]);
            double i23 = pk_fma(xt2, wih[1], bias[1]);
            double i45 = pk_fma(xt2, wih[2], bias[2]);
            double i67 = pk_fma(xt2, wih[3], bias[3]);
            f64x2 ca = {i01, i23}, cb = {i45, i67};
            f32x4 acc0 = __builtin_bit_cast(f32x4, ca);
            f32x4 acc1 = __builtin_bit_cast(f32x4, cb);
            acc0 = __builtin_amdgcn_mfma_f32_16x16x32_f16(a0, hb, acc0, 0, 0, 0);
            acc1 = __builtin_amdgcn_mfma_f32_16x16x32_f16(a1, hb, acc1, 0, 0, 0);
            f64x2 ta = __builtin_bit_cast(f64x2, acc0);
            f64x2 tb = __builtin_bit_cast(f64x2, acc1);

            h01 = tanh_pk(ta[0], k);
            h23 = tanh_pk(ta[1], k);
            h45 = tanh_pk(tb[0], k);
            h67 = tanh_pk(tb[1], k);

            f32x2 v01 = __builtin_bit_cast(f32x2, h01);
            f32x2 v23 = __builtin_bit_cast(f32x2, h23);
            f32x2 v45 = __builtin_bit_cast(f32x2, h45);
            f32x2 v67 = __builtin_bit_cast(f32x2, h67);
            f16x8 nb;
            nb[0] = (_Float16)v01[0]; nb[1] = (_Float16)v01[1];   // v_cvt_f16_f32 RNE
            nb[2] = (_Float16)v23[0]; nb[3] = (_Float16)v23[1];
            nb[4] = (_Float16)v45[0]; nb[5] = (_Float16)v45[1];
            nb[6] = (_Float16)v67[0]; nb[7] = (_Float16)v67[1];
            hb = nb;
        }
        xa = xn;
    }

    // Head: out[r] = sum_c h[r][c] * fc_w[c] + fc_b  (fp32 h values)
    f32x2 v01 = __builtin_bit_cast(f32x2, h01);
    f32x2 v23 = __builtin_bit_cast(f32x2, h23);
    f32x2 v45 = __builtin_bit_cast(f32x2, h45);
    f32x2 v67 = __builtin_bit_cast(f32x2, h67);
    float hv[8] = {v01[0], v01[1], v23[0], v23[1], v45[0], v45[1], v67[0], v67[1]};
    float part = 0.0f;
#pragma unroll
    for (int i = 0; i < 8; ++i) part = fmaf(hv[i], fc_w[8 * q + i], part);
    part += __shfl_xor(part, 16);
    part += __shfl_xor(part, 32);
    if (q == 0) out[blockIdx.x * 16 + n] = part + fc_b[0];
}

extern "C" void kernel_launch(void* const* d_in, const int* in_sizes, int n_in,
                              void* d_out, int out_size, void* d_ws, size_t ws_size,
                              hipStream_t stream) {
    const float* x    = (const float*)d_in[0];
    const float* W_ih = (const float*)d_in[1];
    const float* W_hh = (const float*)d_in[2];
    const float* b_ih = (const float*)d_in[3];
    const float* b_hh = (const float*)d_in[4];
    const float* fc_w = (const float*)d_in[5];
    const float* fc_b = (const float*)d_in[6];
    float* out = (float*)d_out;

    const int B = in_sizes[0] / T_LEN;   // 16384
    rnn_fused<<<B / 16, 64, 0, stream>>>(x, W_ih, W_hh, b_ih, b_hh, fc_w, fc_b, out);
}

// Round 6
// 326.550 us; speedup vs baseline: 1.0536x; 1.0421x over previous
//
#include <hip/hip_runtime.h>

#define T_LEN 1024

typedef _Float16 f16x8 __attribute__((ext_vector_type(8)));
typedef _Float16 f16x2 __attribute__((ext_vector_type(2)));
typedef __fp16   fp16x2 __attribute__((ext_vector_type(2)));
typedef float    f32x4 __attribute__((ext_vector_type(4)));
typedef unsigned short u16x2 __attribute__((ext_vector_type(2)));

// Packed-f16 tanh with pre-scaled input t = 2*log2(e)*v (K folded into MFMA A/C).
// tanh(v) = 1 - 2/(exp2(t)+1).
//  - clamp t to [-14, 11]  (avoids f16 overflow of 2^t; err <= 9.7e-4 at saturation)
//  - magic-add RNE split t = i + f (magic 1.5*2^10), f in [-0.5, 0.5]
//  - 2^f: deg-4 Taylor (rel err ~4e-5)
//  - 2^i exact: bits = (bits(m)<<10) + 0x3C00   [= (i+15)<<10 for i in [-14,16]]
//  - 1/(E+1): u16 magic seed 0x7798 - bits(d) (~5% err) + 2 Newton
// Everything lowers to v_pk_*_f16 / v_pk_*_16 (2 elems/instr), zero trans-pipe ops.
__device__ __forceinline__ f16x2 tanh_pk(f16x2 t) {
    const f16x2 LO   = {(_Float16)-14.0f, (_Float16)-14.0f};
    const f16x2 HI   = {(_Float16)11.0f,  (_Float16)11.0f};
    const f16x2 MAG  = {(_Float16)1536.0f, (_Float16)1536.0f};
    const f16x2 ONE  = {(_Float16)1.0f, (_Float16)1.0f};
    const f16x2 TWO  = {(_Float16)2.0f, (_Float16)2.0f};
    const f16x2 NTWO = {(_Float16)-2.0f, (_Float16)-2.0f};
    const f16x2 C1 = {(_Float16)0.69314718f, (_Float16)0.69314718f};
    const f16x2 C2 = {(_Float16)0.24022651f, (_Float16)0.24022651f};
    const f16x2 C3 = {(_Float16)0.05550411f, (_Float16)0.05550411f};
    const f16x2 C4 = {(_Float16)0.00961813f, (_Float16)0.00961813f};

    t = __builtin_elementwise_max(t, LO);
    t = __builtin_elementwise_min(t, HI);
    f16x2 m  = t + MAG;            // RNE to integer
    f16x2 fi = m - MAG;            // i as f16
    f16x2 f  = t - fi;             // exact, in [-0.5, 0.5]
    u16x2 mb = __builtin_bit_cast(u16x2, m);
    u16x2 sb = (u16x2)(mb << 10) + (u16x2){0x3C00, 0x3C00};
    f16x2 scale = __builtin_bit_cast(f16x2, sb);        // 2^i exact
    f16x2 p = __builtin_elementwise_fma(f, C4, C3);
    p = __builtin_elementwise_fma(f, p, C2);
    p = __builtin_elementwise_fma(f, p, C1);
    p = __builtin_elementwise_fma(f, p, ONE);           // 2^f
    f16x2 E = scale * p;                                 // exp2(t)
    f16x2 d = E + ONE;
    u16x2 rb = (u16x2){0x7798, 0x7798} - __builtin_bit_cast(u16x2, d);
    f16x2 r = __builtin_bit_cast(f16x2, rb);             // ~5% rcp seed
    f16x2 q1 = __builtin_elementwise_fma(-d, r, TWO);
    r = r * q1;
    f16x2 q2 = __builtin_elementwise_fma(-d, r, TWO);
    r = r * q2;                                          // 1/(E+1), ~f16-exact
    return __builtin_elementwise_fma(r, NTWO, ONE);      // 1 - 2r
}

// One wave (64 threads) per block; block owns 16 batch rows for all T steps.
// Recurrence as C[m][n] = sum_k Whh[sigma(m)][k] * h[n][k] via mfma_f32_16x16x32_f16:
//   A-frag: A[m=lane&15][k=quad*8+j] = K*Whh[sigma(m)][k]  (static, f16, K=2log2e folded)
//   B-frag: B[k=quad*8+j][n=lane&15] = h[row n][k]         (recirculated in-register)
//   C-frag: col n=lane&15 (batch row), row m=quad*4+reg (h index via sigma)
// sigma0(m)=8*(m>>2)+(m&3), sigma1=sigma0+4  ==> lane's C outputs are exactly
// h[n][8*quad + 0..7] == its own B-fragment slots for the next step. No LDS/shuffle.
__global__ __launch_bounds__(64) void rnn_fused(
    const float* __restrict__ x,      // [B, T]
    const float* __restrict__ W_ih,   // [32,1]
    const float* __restrict__ W_hh,   // [32,32]
    const float* __restrict__ b_ih,   // [32]
    const float* __restrict__ b_hh,   // [32]
    const float* __restrict__ fc_w,   // [1,32]
    const float* __restrict__ fc_b,   // [1]
    float* __restrict__ out)          // [B]
{
    const int lane = threadIdx.x;
    const int n = lane & 15;   // batch row within tile (B-frag col / C col)
    const int q = lane >> 4;   // quad index

    const float K = 2.88539008177792681472f;   // 2*log2(e)

    // A fragments (W_hh rows, permuted by sigma), pre-scaled by K, f16.
    const int c0row = 8 * (n >> 2) + (n & 3);
    const int c1row = c0row + 4;
    f16x8 a0, a1;
#pragma unroll
    for (int j = 0; j < 8; ++j) {
        a0[j] = (_Float16)(K * W_hh[c0row * 32 + q * 8 + j]);
        a1[j] = (_Float16)(K * W_hh[c1row * 32 + q * 8 + j]);
    }

    // This lane produces h-columns c = 8q + i (i = 0..7).
    float wih[8], bias[8];
#pragma unroll
    for (int i = 0; i < 8; ++i) {
        int c = 8 * q + i;
        wih[i]  = K * W_ih[c];
        bias[i] = K * (b_ih[c] + b_hh[c]);
    }

    const float* xrow = x + (size_t)(blockIdx.x * 16 + n) * T_LEN;
    float4 xa = *(const float4*)xrow;   // t = 0..3 (4 lanes/row redundant -> broadcast)

    f16x8 hb = {};          // B fragment: h[n][8q+j], starts at 0

    for (int t4 = 0; t4 < T_LEN / 4; ++t4) {
        const int nt4 = (t4 < T_LEN / 4 - 1) ? t4 + 1 : t4;   // prefetch next x chunk
        float4 xn = *(const float4*)(xrow + (size_t)nt4 * 4);
#pragma unroll
        for (int p = 0; p < 4; ++p) {
            const float xt = (p == 0) ? xa.x : (p == 1) ? xa.y : (p == 2) ? xa.z : xa.w;
            f32x4 acc0, acc1;
#pragma unroll
            for (int i = 0; i < 4; ++i) {
                acc0[i] = fmaf(xt, wih[i],     bias[i]);   // C-init = K*(x*W_ih + b)
                acc1[i] = fmaf(xt, wih[4 + i], bias[4 + i]);
            }
            acc0 = __builtin_amdgcn_mfma_f32_16x16x32_f16(a0, hb, acc0, 0, 0, 0);
            acc1 = __builtin_amdgcn_mfma_f32_16x16x32_f16(a1, hb, acc1, 0, 0, 0);

            // f32 -> packed f16 (RTZ; err on t maps through sech^2 -> <=5e-4 on h)
            fp16x2 c01 = __builtin_amdgcn_cvt_pkrtz(acc0[0], acc0[1]);
            fp16x2 c23 = __builtin_amdgcn_cvt_pkrtz(acc0[2], acc0[3]);
            fp16x2 c45 = __builtin_amdgcn_cvt_pkrtz(acc1[0], acc1[1]);
            fp16x2 c67 = __builtin_amdgcn_cvt_pkrtz(acc1[2], acc1[3]);

            f16x2 h01 = tanh_pk(__builtin_bit_cast(f16x2, c01));
            f16x2 h23 = tanh_pk(__builtin_bit_cast(f16x2, c23));
            f16x2 h45 = tanh_pk(__builtin_bit_cast(f16x2, c45));
            f16x2 h67 = tanh_pk(__builtin_bit_cast(f16x2, c67));

            struct H4 { f16x2 p[4]; } hh;
            hh.p[0] = h01; hh.p[1] = h23; hh.p[2] = h45; hh.p[3] = h67;
            hb = __builtin_bit_cast(f16x8, hh);   // pairs are VGPR-aligned: free
        }
        xa = xn;
    }

    // Head: out[r] = sum_c h[r][c] * fc_w[c] + fc_b   (h from f16 fragment)
    float part = 0.0f;
#pragma unroll
    for (int i = 0; i < 8; ++i) part = fmaf((float)hb[i], fc_w[8 * q + i], part);
    part += __shfl_xor(part, 16);
    part += __shfl_xor(part, 32);
    if (q == 0) out[blockIdx.x * 16 + n] = part + fc_b[0];
}

extern "C" void kernel_launch(void* const* d_in, const int* in_sizes, int n_in,
                              void* d_out, int out_size, void* d_ws, size_t ws_size,
                              hipStream_t stream) {
    const float* x    = (const float*)d_in[0];
    const float* W_ih = (const float*)d_in[1];
    const float* W_hh = (const float*)d_in[2];
    const float* b_ih = (const float*)d_in[3];
    const float* b_hh = (const float*)d_in[4];
    const float* fc_w = (const float*)d_in[5];
    const float* fc_b = (const float*)d_in[6];
    float* out = (float*)d_out;

    const int B = in_sizes[0] / T_LEN;   // 16384
    rnn_fused<<<B / 16, 64, 0, stream>>>(x, W_ih, W_hh, b_ih, b_hh, fc_w, fc_b, out);
}

// Round 7
// 264.145 us; speedup vs baseline: 1.3026x; 1.2363x over previous
//
#include <hip/hip_runtime.h>

#define T_LEN 1024

typedef _Float16 f16x8 __attribute__((ext_vector_type(8)));
typedef __fp16   fp16x2 __attribute__((ext_vector_type(2)));
typedef float    f32x4 __attribute__((ext_vector_type(4)));

// One wave (64 threads) per block; block owns 16 batch rows for all T steps.
// Recurrence as C[m][n] = sum_k Whh[sigma(m)][k] * h[n][k] via mfma_f32_16x16x32_f16:
//   A-frag: A[m=lane&15][k=quad*8+j] = K*Whh[sigma(m)][k]  (static, f16, K=2log2e folded)
//   B-frag: B[k=quad*8+j][n=lane&15] = h[row n][k]         (recirculated in-register)
//   C-frag: col n=lane&15 (batch row), row m=quad*4+reg (h index via sigma)
// sigma0(m)=8*(m>>2)+(m&3), sigma1=sigma0+4  ==> lane's C outputs are exactly
// h[n][8*quad + 0..7] == its own B-fragment slots for the next step. No LDS/shuffle.
//
// tanh via hardware trans pipe (quarter-rate, but cheaper than any software
// variant on this compiler — r4/r5/r6 all scalarized):
//   acc = K*v (K folded) ; E = v_exp_f32(acc) = exp(2v) ; h = 1 - 2*rcp(E+1).
__global__ __launch_bounds__(64) void rnn_fused(
    const float* __restrict__ x,      // [B, T]
    const float* __restrict__ W_ih,   // [32,1]
    const float* __restrict__ W_hh,   // [32,32]
    const float* __restrict__ b_ih,   // [32]
    const float* __restrict__ b_hh,   // [32]
    const float* __restrict__ fc_w,   // [1,32]
    const float* __restrict__ fc_b,   // [1]
    float* __restrict__ out)          // [B]
{
    const int lane = threadIdx.x;
    const int n = lane & 15;   // batch row within tile (B-frag col / C col)
    const int q = lane >> 4;   // quad index

    const float K = 2.88539008177792681472f;   // 2*log2(e), folded into A and C-init

    // A fragments (W_hh rows, permuted by sigma), pre-scaled by K, f16.
    const int c0row = 8 * (n >> 2) + (n & 3);
    const int c1row = c0row + 4;
    f16x8 a0, a1;
#pragma unroll
    for (int j = 0; j < 8; ++j) {
        a0[j] = (_Float16)(K * W_hh[c0row * 32 + q * 8 + j]);
        a1[j] = (_Float16)(K * W_hh[c1row * 32 + q * 8 + j]);
    }

    // This lane produces h-columns c = 8q + i (i = 0..7).
    float wih[8], bias[8];
#pragma unroll
    for (int i = 0; i < 8; ++i) {
        int c = 8 * q + i;
        wih[i]  = K * W_ih[c];
        bias[i] = K * (b_ih[c] + b_hh[c]);
    }

    const float* xrow = x + (size_t)(blockIdx.x * 16 + n) * T_LEN;
    float4 xa = *(const float4*)xrow;   // t = 0..3 (4 lanes/row redundant -> broadcast)

    f16x8 hb = {};          // B fragment: h[n][8q+j], starts at 0

    for (int t4 = 0; t4 < T_LEN / 4; ++t4) {
        const int nt4 = (t4 < T_LEN / 4 - 1) ? t4 + 1 : t4;   // prefetch next x chunk
        float4 xn = *(const float4*)(xrow + (size_t)nt4 * 4);
#pragma unroll
        for (int p = 0; p < 4; ++p) {
            const float xt = (p == 0) ? xa.x : (p == 1) ? xa.y : (p == 2) ? xa.z : xa.w;
            f32x4 acc0, acc1;
#pragma unroll
            for (int i = 0; i < 4; ++i) {
                acc0[i] = fmaf(xt, wih[i],     bias[i]);   // C-init = K*(x*W_ih + b)
                acc1[i] = fmaf(xt, wih[4 + i], bias[4 + i]);
            }
            acc0 = __builtin_amdgcn_mfma_f32_16x16x32_f16(a0, hb, acc0, 0, 0, 0);
            acc1 = __builtin_amdgcn_mfma_f32_16x16x32_f16(a1, hb, acc1, 0, 0, 0);

            // 8 independent exps stream through the quarter-rate trans pipe,
            // then adds, then rcps, then fmas — max ILP inside each stage.
            float e0 = __builtin_amdgcn_exp2f(acc0[0]);
            float e1 = __builtin_amdgcn_exp2f(acc0[1]);
            float e2 = __builtin_amdgcn_exp2f(acc0[2]);
            float e3 = __builtin_amdgcn_exp2f(acc0[3]);
            float e4 = __builtin_amdgcn_exp2f(acc1[0]);
            float e5 = __builtin_amdgcn_exp2f(acc1[1]);
            float e6 = __builtin_amdgcn_exp2f(acc1[2]);
            float e7 = __builtin_amdgcn_exp2f(acc1[3]);
            float d0 = e0 + 1.0f, d1 = e1 + 1.0f, d2 = e2 + 1.0f, d3 = e3 + 1.0f;
            float d4 = e4 + 1.0f, d5 = e5 + 1.0f, d6 = e6 + 1.0f, d7 = e7 + 1.0f;
            float r0 = __builtin_amdgcn_rcpf(d0);
            float r1 = __builtin_amdgcn_rcpf(d1);
            float r2 = __builtin_amdgcn_rcpf(d2);
            float r3 = __builtin_amdgcn_rcpf(d3);
            float r4 = __builtin_amdgcn_rcpf(d4);
            float r5 = __builtin_amdgcn_rcpf(d5);
            float r6 = __builtin_amdgcn_rcpf(d6);
            float r7 = __builtin_amdgcn_rcpf(d7);
            float h0 = fmaf(-2.0f, r0, 1.0f);
            float h1 = fmaf(-2.0f, r1, 1.0f);
            float h2 = fmaf(-2.0f, r2, 1.0f);
            float h3 = fmaf(-2.0f, r3, 1.0f);
            float h4 = fmaf(-2.0f, r4, 1.0f);
            float h5 = fmaf(-2.0f, r5, 1.0f);
            float h6 = fmaf(-2.0f, r6, 1.0f);
            float h7 = fmaf(-2.0f, r7, 1.0f);

            // pack pairs directly: 4 x v_cvt_pkrtz_f16_f32
            struct H4 { fp16x2 p[4]; } hh;
            hh.p[0] = __builtin_amdgcn_cvt_pkrtz(h0, h1);
            hh.p[1] = __builtin_amdgcn_cvt_pkrtz(h2, h3);
            hh.p[2] = __builtin_amdgcn_cvt_pkrtz(h4, h5);
            hh.p[3] = __builtin_amdgcn_cvt_pkrtz(h6, h7);
            hb = __builtin_bit_cast(f16x8, hh);
        }
        xa = xn;
    }

    // Head: out[r] = sum_c h[r][c] * fc_w[c] + fc_b   (h from f16 fragment)
    float part = 0.0f;
#pragma unroll
    for (int i = 0; i < 8; ++i) part = fmaf((float)hb[i], fc_w[8 * q + i], part);
    part += __shfl_xor(part, 16);
    part += __shfl_xor(part, 32);
    if (q == 0) out[blockIdx.x * 16 + n] = part + fc_b[0];
}

extern "C" void kernel_launch(void* const* d_in, const int* in_sizes, int n_in,
                              void* d_out, int out_size, void* d_ws, size_t ws_size,
                              hipStream_t stream) {
    const float* x    = (const float*)d_in[0];
    const float* W_ih = (const float*)d_in[1];
    const float* W_hh = (const float*)d_in[2];
    const float* b_ih = (const float*)d_in[3];
    const float* b_hh = (const float*)d_in[4];
    const float* fc_w = (const float*)d_in[5];
    const float* fc_b = (const float*)d_in[6];
    float* out = (float*)d_out;

    const int B = in_sizes[0] / T_LEN;   // 16384
    rnn_fused<<<B / 16, 64, 0, stream>>>(x, W_ih, W_hh, b_ih, b_hh, fc_w, fc_b, out);
}